// Round 3
// baseline (295.651 us; speedup 1.0000x reference)
//
#include <hip/hip_runtime.h>

using short8   = __attribute__((ext_vector_type(8))) short;
using f32x4    = __attribute__((ext_vector_type(4))) float;
using ushort4v = __attribute__((ext_vector_type(4))) unsigned short;

#define BN_EPS 1e-5f
// log2(e)/sqrt(32): folded into q projection so softmax uses native exp2
#define ATT_SCALE_LOG2E 0.2550348347988049f

__device__ __forceinline__ unsigned short f2bf(float f) {
    union { float f; unsigned u; } v; v.f = f;
    return (unsigned short)((v.u + 0x7FFFu + ((v.u >> 16) & 1u)) >> 16);  // RNE
}

// pack two f32 -> two bf16 (round-half-up): a in low 16, b in high 16
__device__ __forceinline__ unsigned pack2bf(float a, float b) {
    union { float f; unsigned u; } ua, ub; ua.f = a; ub.f = b;
    return __builtin_amdgcn_perm(ub.u + 0x8000u, ua.u + 0x8000u, 0x07060302u);
}

// ---------------------------------------------------------------------------
// Kernel 0: weights -> bf16; fold conv-bias + BN into per-row (scale, offset).
// Rows: 0-31 q, 32-63 k, 64-319 v.
// ---------------------------------------------------------------------------
__global__ void prep_kernel(
    const float* __restrict__ qw, const float* __restrict__ qb,
    const float* __restrict__ qg, const float* __restrict__ qbe,
    const float* __restrict__ qm, const float* __restrict__ qv,
    const float* __restrict__ kw, const float* __restrict__ kb,
    const float* __restrict__ kg, const float* __restrict__ kbe,
    const float* __restrict__ km, const float* __restrict__ kvv,
    const float* __restrict__ vw, const float* __restrict__ vb,
    const float* __restrict__ vg, const float* __restrict__ vbe,
    const float* __restrict__ vm, const float* __restrict__ vv,
    unsigned short* __restrict__ wq, float* __restrict__ scale,
    float* __restrict__ off)
{
    int r = blockIdx.x;      // 0..319
    int t = threadIdx.x;     // 0..63
    const float *wsrc, *g, *be, *mn, *vr, *bi;
    int rl;
    if (r < 32)      { rl = r;      wsrc = qw; g = qg; be = qbe; mn = qm; vr = qv;  bi = qb; }
    else if (r < 64) { rl = r - 32; wsrc = kw; g = kg; be = kbe; mn = km; vr = kvv; bi = kb; }
    else             { rl = r - 64; wsrc = vw; g = vg; be = vbe; mn = vm; vr = vv;  bi = vb; }

    float4 w4 = *(const float4*)(wsrc + rl * 256 + t * 4);
    ushort4v o;
    o.x = f2bf(w4.x); o.y = f2bf(w4.y); o.z = f2bf(w4.z); o.w = f2bf(w4.w);
    *(ushort4v*)(wq + r * 256 + t * 4) = o;

    if (t == 0) {
        float inv = g[rl] * rsqrtf(vr[rl] + BN_EPS);
        float ofv = bi[rl] * inv + be[rl] - mn[rl] * inv;
        float s = (r < 32) ? ATT_SCALE_LOG2E : 1.0f;   // q carries softmax+log2e scale
        scale[r] = inv * s;
        off[r]   = ofv * s;
    }
}

// ---------------------------------------------------------------------------
// Kernel 1: projections. bx = (b*64+nt)*3 + g ; g=0: q(x1), g=1: k(x2),
// g=2: all 256 v rows (x2).
// Transpose staging: thread (wave wv, lane) gathers 8 channels for n=lane via
// coalesced dword loads and writes ONE b128 per octet. Pitch 264 shorts
// (132 dwords) makes both b128 writes and reads perfectly bank-uniform.
// ---------------------------------------------------------------------------
#define XT_PITCH 264

__global__ __launch_bounds__(256, 4) void proj_kernel(
    const float* __restrict__ x1, const float* __restrict__ x2,
    const unsigned short* __restrict__ wq,
    const float* __restrict__ scale, const float* __restrict__ off,
    unsigned short* __restrict__ q_t, unsigned short* __restrict__ k_t,
    unsigned short* __restrict__ v_bf)
{
    __shared__ __align__(16) unsigned short Xt[64 * XT_PITCH];   // 33792 B
    int bx = blockIdx.x;
    int g  = bx % 3;
    int t2 = bx / 3;
    int nt = t2 & 63;
    int b  = t2 >> 6;
    int n0 = nt * 64;
    int tid = threadIdx.x;
    int wv = tid >> 6, lane = tid & 63;
    int m16 = lane & 15, qd = lane >> 4;

    const float* xb = ((g == 0) ? x1 : x2) + (size_t)b * 256 * 4096 + n0 + lane;

    // octet-gather transpose: n = lane, channels 8*o..8*o+7, o = wv*8+i
    #pragma unroll
    for (int i = 0; i < 8; ++i) {
        int o = wv * 8 + i;                       // 0..31
        const float* src = xb + (size_t)(o * 8) * 4096;
        uint4 dw;
        dw.x = pack2bf(src[0],          src[(size_t)1 * 4096]);
        dw.y = pack2bf(src[(size_t)2 * 4096], src[(size_t)3 * 4096]);
        dw.z = pack2bf(src[(size_t)4 * 4096], src[(size_t)5 * 4096]);
        dw.w = pack2bf(src[(size_t)6 * 4096], src[(size_t)7 * 4096]);
        *(uint4*)&Xt[lane * XT_PITCH + o * 8] = dw;
    }
    __syncthreads();

    f32x4 zero4 = {0.f, 0.f, 0.f, 0.f};

    if (g < 2) {
        int rb = g * 32;
        f32x4 acc0 = zero4, acc1 = zero4;
        #pragma unroll 2
        for (int s = 0; s < 8; ++s) {
            short8 w0 = *(const short8*)(wq + (size_t)(rb +      m16) * 256 + s * 32 + qd * 8);
            short8 w1 = *(const short8*)(wq + (size_t)(rb + 16 + m16) * 256 + s * 32 + qd * 8);
            short8 xf = *(const short8*)&Xt[(16 * wv + m16) * XT_PITCH + s * 32 + qd * 8];
            acc0 = __builtin_amdgcn_mfma_f32_16x16x32_bf16(w0, xf, acc0, 0, 0, 0);
            acc1 = __builtin_amdgcn_mfma_f32_16x16x32_bf16(w1, xf, acc1, 0, 0, 0);
        }
        unsigned short* dst = (g == 0) ? q_t : k_t;
        int ncol = n0 + 16 * wv + m16;
        #pragma unroll
        for (int tm = 0; tm < 2; ++tm) {
            f32x4 acc = tm ? acc1 : acc0;
            int r0 = 16 * tm + 4 * qd;
            float4 sc = *(const float4*)(scale + rb + r0);
            float4 of = *(const float4*)(off   + rb + r0);
            ushort4v o;
            o.x = f2bf(acc.x * sc.x + of.x);
            o.y = f2bf(acc.y * sc.y + of.y);
            o.z = f2bf(acc.z * sc.z + of.z);
            o.w = f2bf(acc.w * sc.w + of.w);
            *(ushort4v*)(dst + ((size_t)b * 4096 + ncol) * 32 + r0) = o;
        }
    } else {
        f32x4 acc[4][4];
        #pragma unroll
        for (int rr = 0; rr < 4; ++rr)
            #pragma unroll
            for (int tm = 0; tm < 4; ++tm) acc[rr][tm] = zero4;
        #pragma unroll 2
        for (int s = 0; s < 8; ++s) {
            short8 xf[4];
            #pragma unroll
            for (int tm = 0; tm < 4; ++tm)
                xf[tm] = *(const short8*)&Xt[(16 * tm + m16) * XT_PITCH + s * 32 + qd * 8];
            #pragma unroll
            for (int rr = 0; rr < 4; ++rr) {
                short8 wf = *(const short8*)(wq + (size_t)(64 + rr * 64 + 16 * wv + m16) * 256 + s * 32 + qd * 8);
                #pragma unroll
                for (int tm = 0; tm < 4; ++tm)
                    acc[rr][tm] = __builtin_amdgcn_mfma_f32_16x16x32_bf16(xf[tm], wf, acc[rr][tm], 0, 0, 0);
            }
        }
        #pragma unroll
        for (int rr = 0; rr < 4; ++rr) {
            int rglob = 64 + rr * 64 + 16 * wv + m16;
            int c = rglob - 64;
            float sc = scale[rglob], of = off[rglob];
            #pragma unroll
            for (int tm = 0; tm < 4; ++tm) {
                int nloc = 16 * tm + 4 * qd;
                ushort4v o;
                o.x = f2bf(acc[rr][tm].x * sc + of);
                o.y = f2bf(acc[rr][tm].y * sc + of);
                o.z = f2bf(acc[rr][tm].z * sc + of);
                o.w = f2bf(acc[rr][tm].w * sc + of);
                *(ushort4v*)(v_bf + ((size_t)b * 256 + c) * 4096 + n0 + nloc) = o;
            }
        }
    }
}

// ---------------------------------------------------------------------------
// Kernel 2: flash attention, key-split x2 for occupancy.
// 1024 blocks (4/CU) x 4 waves (16 waves/CU). Block = 64 queries x 64
// channels x all keys; wave (qh, ks) = 32 queries x 2048 keys. Main loop is
// barrier-free (wave-private P in LDS, S^T trick). Row-sums come from an
// extra MFMA vs a ones B-fragment (no VALU adds, no shuffle epilogue).
// Key-split halves combine once at the end through LDS (2 barriers total).
// ---------------------------------------------------------------------------
#define PP 72

__global__ __launch_bounds__(256, 4) void flash_kernel(
    const unsigned short* __restrict__ q_t, const unsigned short* __restrict__ k_t,
    const unsigned short* __restrict__ v_bf, float* __restrict__ out)
{
    __shared__ __align__(16) unsigned short Plds[4 * 2 * 32 * PP];   // 36864 B

    int bx  = blockIdx.x;
    int cg  = bx & 3;
    int b   = (bx >> 2) & 3;
    int qg  = bx >> 4;             // 0..63
    int tid = threadIdx.x;
    int wv = tid >> 6, lane = tid & 63;
    int m16 = lane & 15, qd = lane >> 4;
    int qh = wv & 1, ks = wv >> 1;

    int q0 = qg * 64 + qh * 32;
    int c0 = cg * 64;

    const unsigned short* qb = q_t + (size_t)b * 4096 * 32;
    const unsigned short* kb = k_t + ((size_t)b * 4096 + ks * 2048) * 32;
    const unsigned short* vb = v_bf + ((size_t)b * 256 + c0) * 4096 + ks * 2048;

    short8 Qf0 = *(const short8*)(qb + (size_t)(q0 +      m16) * 32 + qd * 8);
    short8 Qf1 = *(const short8*)(qb + (size_t)(q0 + 16 + m16) * 32 + qd * 8);

    const short bf1 = (short)0x3F80;   // bf16 1.0
    short8 ones = {bf1, bf1, bf1, bf1, bf1, bf1, bf1, bf1};

    f32x4 zero4 = {0.f, 0.f, 0.f, 0.f};
    f32x4 acc[2][4];
    f32x4 Do[2] = {zero4, zero4};
    #pragma unroll
    for (int mt = 0; mt < 2; ++mt)
        #pragma unroll
        for (int cs = 0; cs < 4; ++cs) acc[mt][cs] = zero4;

    unsigned short* Pbase = &Plds[wv * (2 * 32 * PP)];

    #pragma unroll 2
    for (int it = 0; it < 32; ++it) {
        int n0 = it * 64;
        unsigned short* Pw = Pbase + (it & 1) * (32 * PP);

        // ---- global loads (L2-resident) ----
        short8 Kf[4];
        #pragma unroll
        for (int s = 0; s < 4; ++s)
            Kf[s] = *(const short8*)(kb + (size_t)(n0 + s * 16 + m16) * 32 + qd * 8);
        short8 Vf[4][2];
        #pragma unroll
        for (int cs = 0; cs < 4; ++cs)
            #pragma unroll
            for (int t = 0; t < 2; ++t)
                Vf[cs][t] = *(const short8*)(vb + (size_t)(cs * 16 + m16) * 4096 + n0 + t * 32 + qd * 8);

        // ---- S^T = K.Q^T (col=query, 4 consecutive keys per lane) ----
        f32x4 St0[4], St1[4];
        #pragma unroll
        for (int s = 0; s < 4; ++s) {
            St0[s] = __builtin_amdgcn_mfma_f32_16x16x32_bf16(Kf[s], Qf0, zero4, 0, 0, 0);
            St1[s] = __builtin_amdgcn_mfma_f32_16x16x32_bf16(Kf[s], Qf1, zero4, 0, 0, 0);
        }

        // ---- exp2 + pack + wave-private P write (no barrier) ----
        #pragma unroll
        for (int s = 0; s < 4; ++s) {
            float a0 = __builtin_amdgcn_exp2f(St0[s].x), a1 = __builtin_amdgcn_exp2f(St0[s].y);
            float a2 = __builtin_amdgcn_exp2f(St0[s].z), a3 = __builtin_amdgcn_exp2f(St0[s].w);
            uint2 w0; w0.x = pack2bf(a0, a1); w0.y = pack2bf(a2, a3);
            *(uint2*)&Pw[(     m16) * PP + s * 16 + qd * 4] = w0;
            float b0 = __builtin_amdgcn_exp2f(St1[s].x), b1 = __builtin_amdgcn_exp2f(St1[s].y);
            float b2 = __builtin_amdgcn_exp2f(St1[s].z), b3 = __builtin_amdgcn_exp2f(St1[s].w);
            uint2 w1; w1.x = pack2bf(b0, b1); w1.y = pack2bf(b2, b3);
            *(uint2*)&Pw[(16 + m16) * PP + s * 16 + qd * 4] = w1;
        }

        // ---- read own A-frags back (same-wave lgkm dependency only) ----
        short8 Ap[2][2];
        #pragma unroll
        for (int mt = 0; mt < 2; ++mt)
            #pragma unroll
            for (int t = 0; t < 2; ++t)
                Ap[mt][t] = *(const short8*)&Pw[(mt * 16 + m16) * PP + t * 32 + qd * 8];

        // ---- PV + ones-column row-sum ----
        #pragma unroll
        for (int t = 0; t < 2; ++t) {
            Do[0] = __builtin_amdgcn_mfma_f32_16x16x32_bf16(Ap[0][t], ones, Do[0], 0, 0, 0);
            Do[1] = __builtin_amdgcn_mfma_f32_16x16x32_bf16(Ap[1][t], ones, Do[1], 0, 0, 0);
            #pragma unroll
            for (int cs = 0; cs < 4; ++cs) {
                acc[0][cs] = __builtin_amdgcn_mfma_f32_16x16x32_bf16(Ap[0][t], Vf[cs][t], acc[0][cs], 0, 0, 0);
                acc[1][cs] = __builtin_amdgcn_mfma_f32_16x16x32_bf16(Ap[1][t], Vf[cs][t], acc[1][cs], 0, 0, 0);
            }
        }
    }

    // ---- combine key-split halves through LDS (stride 44 floats: 4-way max) ----
    __syncthreads();
    float* red = (float*)Plds;
    if (wv >= 2) {
        float* dst = red + (size_t)(wv - 2) * (64 * 44) + lane * 44;
        #pragma unroll
        for (int mt = 0; mt < 2; ++mt)
            #pragma unroll
            for (int cs = 0; cs < 4; ++cs)
                *(f32x4*)&dst[(mt * 4 + cs) * 4] = acc[mt][cs];
        *(f32x4*)&dst[32] = Do[0];
        *(f32x4*)&dst[36] = Do[1];
    }
    __syncthreads();
    if (wv < 2) {
        float* src = red + (size_t)wv * (64 * 44) + lane * 44;
        #pragma unroll
        for (int mt = 0; mt < 2; ++mt)
            #pragma unroll
            for (int cs = 0; cs < 4; ++cs) {
                f32x4 p = *(const f32x4*)&src[(mt * 4 + cs) * 4];
                acc[mt][cs].x += p.x; acc[mt][cs].y += p.y;
                acc[mt][cs].z += p.z; acc[mt][cs].w += p.w;
            }
        f32x4 d0 = *(const f32x4*)&src[32];
        f32x4 d1 = *(const f32x4*)&src[36];
        Do[0].x += d0.x; Do[0].y += d0.y; Do[0].z += d0.z; Do[0].w += d0.w;
        Do[1].x += d1.x; Do[1].y += d1.y; Do[1].z += d1.z; Do[1].w += d1.w;

        f32x4 inv[2];
        #pragma unroll
        for (int mt = 0; mt < 2; ++mt) {
            inv[mt].x = __builtin_amdgcn_rcpf(Do[mt].x);
            inv[mt].y = __builtin_amdgcn_rcpf(Do[mt].y);
            inv[mt].z = __builtin_amdgcn_rcpf(Do[mt].z);
            inv[mt].w = __builtin_amdgcn_rcpf(Do[mt].w);
        }

        float* ob = out + ((size_t)b * 256 + c0) * 4096 + q0;
        #pragma unroll
        for (int mt = 0; mt < 2; ++mt)
            #pragma unroll
            for (int cs = 0; cs < 4; ++cs) {
                float4 o;
                o.x = acc[mt][cs].x * inv[mt].x;
                o.y = acc[mt][cs].y * inv[mt].y;
                o.z = acc[mt][cs].z * inv[mt].z;
                o.w = acc[mt][cs].w * inv[mt].w;
                *(float4*)(ob + (size_t)(cs * 16 + m16) * 4096 + mt * 16 + qd * 4) = o;
            }
    }
}

// ---------------------------------------------------------------------------
// Workspace: wq 320x256 bf16 | scale/off 320 f32 | q_t,k_t [b][n][32] bf16 |
// v_bf [b][c][n] bf16. Total ~10.7 MB.
// ---------------------------------------------------------------------------
extern "C" void kernel_launch(void* const* d_in, const int* in_sizes, int n_in,
                              void* d_out, int out_size, void* d_ws, size_t ws_size,
                              hipStream_t stream)
{
    const float* x1  = (const float*)d_in[0];
    const float* x2  = (const float*)d_in[1];
    const float* qw  = (const float*)d_in[2];
    const float* qb  = (const float*)d_in[3];
    const float* qg  = (const float*)d_in[4];
    const float* qbe = (const float*)d_in[5];
    const float* qm  = (const float*)d_in[6];
    const float* qv  = (const float*)d_in[7];
    const float* kw  = (const float*)d_in[8];
    const float* kb  = (const float*)d_in[9];
    const float* kg  = (const float*)d_in[10];
    const float* kbe = (const float*)d_in[11];
    const float* km  = (const float*)d_in[12];
    const float* kvv = (const float*)d_in[13];
    const float* vw  = (const float*)d_in[14];
    const float* vb  = (const float*)d_in[15];
    const float* vg  = (const float*)d_in[16];
    const float* vbe = (const float*)d_in[17];
    const float* vm  = (const float*)d_in[18];
    const float* vv  = (const float*)d_in[19];

    char* ws = (char*)d_ws;
    unsigned short* wq   = (unsigned short*)(ws + 0);
    float*          scale= (float*)(ws + 163840);
    float*          off  = (float*)(ws + 165120);
    unsigned short* q_t  = (unsigned short*)(ws + 166400);
    unsigned short* k_t  = (unsigned short*)(ws + 166400 + 1048576);
    unsigned short* v_bf = (unsigned short*)(ws + 166400 + 2097152);

    prep_kernel<<<320, 64, 0, stream>>>(qw, qb, qg, qbe, qm, qv,
                                        kw, kb, kg, kbe, km, kvv,
                                        vw, vb, vg, vbe, vm, vv,
                                        wq, scale, off);
    proj_kernel<<<768, 256, 0, stream>>>(x1, x2, wq, scale, off, q_t, k_t, v_bf);
    flash_kernel<<<1024, 256, 0, stream>>>(q_t, k_t, v_bf, (float*)d_out);
}

// Round 4
// 277.109 us; speedup vs baseline: 1.0669x; 1.0669x over previous
//
#include <hip/hip_runtime.h>

using short8   = __attribute__((ext_vector_type(8))) short;
using f32x4    = __attribute__((ext_vector_type(4))) float;
using ushort4v = __attribute__((ext_vector_type(4))) unsigned short;

#define BN_EPS 1e-5f
// log2(e)/sqrt(32): folded into q projection so softmax uses native exp2
#define ATT_SCALE_LOG2E 0.2550348347988049f

__device__ __forceinline__ unsigned short f2bf(float f) {
    union { float f; unsigned u; } v; v.f = f;
    return (unsigned short)((v.u + 0x7FFFu + ((v.u >> 16) & 1u)) >> 16);  // RNE
}

// pack two f32 -> two bf16 (round-half-up): a in low 16, b in high 16
__device__ __forceinline__ unsigned pack2bf(float a, float b) {
    union { float f; unsigned u; } ua, ub; ua.f = a; ub.f = b;
    return __builtin_amdgcn_perm(ub.u + 0x8000u, ua.u + 0x8000u, 0x07060302u);
}

// ---------------------------------------------------------------------------
// Kernel 0: weights -> bf16; fold conv-bias + BN into per-row (scale, offset).
// Rows: 0-31 q, 32-63 k, 64-319 v.
// ---------------------------------------------------------------------------
__global__ void prep_kernel(
    const float* __restrict__ qw, const float* __restrict__ qb,
    const float* __restrict__ qg, const float* __restrict__ qbe,
    const float* __restrict__ qm, const float* __restrict__ qv,
    const float* __restrict__ kw, const float* __restrict__ kb,
    const float* __restrict__ kg, const float* __restrict__ kbe,
    const float* __restrict__ km, const float* __restrict__ kvv,
    const float* __restrict__ vw, const float* __restrict__ vb,
    const float* __restrict__ vg, const float* __restrict__ vbe,
    const float* __restrict__ vm, const float* __restrict__ vv,
    unsigned short* __restrict__ wq, float* __restrict__ scale,
    float* __restrict__ off)
{
    int r = blockIdx.x;      // 0..319
    int t = threadIdx.x;     // 0..63
    const float *wsrc, *g, *be, *mn, *vr, *bi;
    int rl;
    if (r < 32)      { rl = r;      wsrc = qw; g = qg; be = qbe; mn = qm; vr = qv;  bi = qb; }
    else if (r < 64) { rl = r - 32; wsrc = kw; g = kg; be = kbe; mn = km; vr = kvv; bi = kb; }
    else             { rl = r - 64; wsrc = vw; g = vg; be = vbe; mn = vm; vr = vv;  bi = vb; }

    float4 w4 = *(const float4*)(wsrc + rl * 256 + t * 4);
    ushort4v o;
    o.x = f2bf(w4.x); o.y = f2bf(w4.y); o.z = f2bf(w4.z); o.w = f2bf(w4.w);
    *(ushort4v*)(wq + r * 256 + t * 4) = o;

    if (t == 0) {
        float inv = g[rl] * rsqrtf(vr[rl] + BN_EPS);
        float ofv = bi[rl] * inv + be[rl] - mn[rl] * inv;
        float s = (r < 32) ? ATT_SCALE_LOG2E : 1.0f;   // q carries softmax+log2e scale
        scale[r] = inv * s;
        off[r]   = ofv * s;
    }
}

// ---------------------------------------------------------------------------
// Kernel 1: projections. bx = ((b*64+nt)<<2) | g ; g=0: q(x1), g=1: k(x2),
// g=2: v rows 0-127 (x2), g=3: v rows 128-255 (x2).
// q_t/k_t: [b][n][32] bf16.  v_ws: TILE-BLOCKED [b*64+nt][256][64] bf16 so
// flash reads each key-tile's V as one contiguous 32KB block.
// ---------------------------------------------------------------------------
#define XT_PITCH 264

__global__ __launch_bounds__(256, 4) void proj_kernel(
    const float* __restrict__ x1, const float* __restrict__ x2,
    const unsigned short* __restrict__ wq,
    const float* __restrict__ scale, const float* __restrict__ off,
    unsigned short* __restrict__ q_t, unsigned short* __restrict__ k_t,
    unsigned short* __restrict__ v_ws)
{
    __shared__ __align__(16) unsigned short Xt[64 * XT_PITCH];   // 33792 B
    int bx = blockIdx.x;
    int g  = bx & 3;
    int t2 = bx >> 2;
    int nt = t2 & 63;
    int b  = t2 >> 6;
    int n0 = nt * 64;
    int tid = threadIdx.x;
    int wv = tid >> 6, lane = tid & 63;
    int m16 = lane & 15, qd = lane >> 4;

    const float* xb = ((g == 0) ? x1 : x2) + (size_t)b * 256 * 4096 + n0 + lane;

    // octet-gather transpose: n = lane, channels 8*o..8*o+7, o = wv*8+i
    #pragma unroll 2
    for (int i = 0; i < 8; ++i) {
        int o = wv * 8 + i;                       // 0..31
        const float* src = xb + (size_t)(o * 8) * 4096;
        uint4 dw;
        dw.x = pack2bf(src[0],                src[(size_t)1 * 4096]);
        dw.y = pack2bf(src[(size_t)2 * 4096], src[(size_t)3 * 4096]);
        dw.z = pack2bf(src[(size_t)4 * 4096], src[(size_t)5 * 4096]);
        dw.w = pack2bf(src[(size_t)6 * 4096], src[(size_t)7 * 4096]);
        *(uint4*)&Xt[lane * XT_PITCH + o * 8] = dw;
    }
    __syncthreads();

    f32x4 zero4 = {0.f, 0.f, 0.f, 0.f};

    if (g < 2) {
        int rb = g * 32;
        f32x4 acc0 = zero4, acc1 = zero4;
        #pragma unroll 2
        for (int s = 0; s < 8; ++s) {
            short8 w0 = *(const short8*)(wq + (size_t)(rb +      m16) * 256 + s * 32 + qd * 8);
            short8 w1 = *(const short8*)(wq + (size_t)(rb + 16 + m16) * 256 + s * 32 + qd * 8);
            short8 xf = *(const short8*)&Xt[(16 * wv + m16) * XT_PITCH + s * 32 + qd * 8];
            acc0 = __builtin_amdgcn_mfma_f32_16x16x32_bf16(w0, xf, acc0, 0, 0, 0);
            acc1 = __builtin_amdgcn_mfma_f32_16x16x32_bf16(w1, xf, acc1, 0, 0, 0);
        }
        unsigned short* dst = (g == 0) ? q_t : k_t;
        int ncol = n0 + 16 * wv + m16;
        #pragma unroll
        for (int tm = 0; tm < 2; ++tm) {
            f32x4 acc = tm ? acc1 : acc0;
            int r0 = 16 * tm + 4 * qd;
            float4 sc = *(const float4*)(scale + rb + r0);
            float4 of = *(const float4*)(off   + rb + r0);
            ushort4v o;
            o.x = f2bf(acc.x * sc.x + of.x);
            o.y = f2bf(acc.y * sc.y + of.y);
            o.z = f2bf(acc.z * sc.z + of.z);
            o.w = f2bf(acc.w * sc.w + of.w);
            *(ushort4v*)(dst + ((size_t)b * 4096 + ncol) * 32 + r0) = o;
        }
    } else {
        int cb = (g - 2) * 128;    // v channel base (weight row 64+cb)
        f32x4 acc[2][4];
        #pragma unroll
        for (int rr = 0; rr < 2; ++rr)
            #pragma unroll
            for (int tm = 0; tm < 4; ++tm) acc[rr][tm] = zero4;
        #pragma unroll 2
        for (int s = 0; s < 8; ++s) {
            short8 xf[4];
            #pragma unroll
            for (int tm = 0; tm < 4; ++tm)
                xf[tm] = *(const short8*)&Xt[(16 * tm + m16) * XT_PITCH + s * 32 + qd * 8];
            #pragma unroll
            for (int rr = 0; rr < 2; ++rr) {
                short8 wf = *(const short8*)(wq + (size_t)(64 + cb + rr * 64 + 16 * wv + m16) * 256 + s * 32 + qd * 8);
                #pragma unroll
                for (int tm = 0; tm < 4; ++tm)
                    acc[rr][tm] = __builtin_amdgcn_mfma_f32_16x16x32_bf16(xf[tm], wf, acc[rr][tm], 0, 0, 0);
            }
        }
        unsigned short* vt = v_ws + (size_t)(b * 64 + nt) * 256 * 64;
        #pragma unroll
        for (int rr = 0; rr < 2; ++rr) {
            int c = cb + rr * 64 + 16 * wv + m16;
            float sc = scale[64 + c], of = off[64 + c];
            #pragma unroll
            for (int tm = 0; tm < 4; ++tm) {
                int nloc = 16 * tm + 4 * qd;
                ushort4v o;
                o.x = f2bf(acc[rr][tm].x * sc + of);
                o.y = f2bf(acc[rr][tm].y * sc + of);
                o.z = f2bf(acc[rr][tm].z * sc + of);
                o.w = f2bf(acc[rr][tm].w * sc + of);
                *(ushort4v*)(vt + c * 64 + nloc) = o;
            }
        }
    }
}

// ---------------------------------------------------------------------------
// Kernel 2: flash attention. 1024 blocks x 4 waves (4 blocks/CU, 16 waves/CU).
// Wave (qh,ks) = 32 queries x 2048 keys. Key-tile processed in two 32-key
// halves (rolled loop) to keep peak live regs <=128 -> NO SPILL at 4 blk/CU.
// P: wave-private, XOR-swizzled (chunk^=m16&7, pitch 64 shorts): both the
// b64 writes and b128 reads are bank-uniform at the structural floor.
// Row-sums via ones-MFMA; key-split halves combine via LDS at the end.
// ---------------------------------------------------------------------------
__global__ __launch_bounds__(256, 4) void flash_kernel(
    const unsigned short* __restrict__ q_t, const unsigned short* __restrict__ k_t,
    const unsigned short* __restrict__ v_ws, float* __restrict__ out)
{
    __shared__ __align__(16) unsigned char Smem[22528];  // P: 16KB; epilogue: 22KB
    unsigned short* Plds = (unsigned short*)Smem;

    int bx  = blockIdx.x;
    int cg  = bx & 3;
    int b   = (bx >> 2) & 3;
    int qg  = bx >> 4;             // 0..63
    int tid = threadIdx.x;
    int wv = tid >> 6, lane = tid & 63;
    int m16 = lane & 15, qd = lane >> 4;
    int qh = wv & 1, ks = wv >> 1;

    int q0 = qg * 64 + qh * 32;
    int c0 = cg * 64;
    int sw = m16 & 7;

    const unsigned short* qb  = q_t + (size_t)b * 4096 * 32;
    const unsigned short* kp  = k_t + ((size_t)b * 4096 + ks * 2048 + m16) * 32 + qd * 8;
    const unsigned short* vpA = v_ws + ((size_t)(b * 64 + ks * 32) * 256 + c0 + m16) * 64 + qd * 8;
    const unsigned short* vpB = vpA + 2048;      // +2 channel-groups (cs=2,3)

    short8 Qf0 = *(const short8*)(qb + (size_t)(q0 +      m16) * 32 + qd * 8);
    short8 Qf1 = *(const short8*)(qb + (size_t)(q0 + 16 + m16) * 32 + qd * 8);

    const short bf1 = (short)0x3F80;
    short8 ones = {bf1, bf1, bf1, bf1, bf1, bf1, bf1, bf1};

    f32x4 zero4 = {0.f, 0.f, 0.f, 0.f};
    f32x4 acc[2][4];
    f32x4 Do[2] = {zero4, zero4};
    #pragma unroll
    for (int mt = 0; mt < 2; ++mt)
        #pragma unroll
        for (int cs = 0; cs < 4; ++cs) acc[mt][cs] = zero4;

    unsigned short* Pw = Plds + wv * (32 * 64);
    int wr0 = m16 * 64 + (qd & 1) * 4;          // P write base: query half 0
    int wr1 = wr0 + 16 * 64;                    //              query half 1
    int ch  = qd >> 1;                          // write chunk low bit source
    int rdc = qd;                               // read chunk = 4t + qd

    #pragma unroll 1
    for (int it = 0; it < 32; ++it) {
        #pragma unroll 1
        for (int t = 0; t < 2; ++t) {
            // ---- loads for this 32-key half (L2-resident) ----
            short8 Kf0 = *(const short8*)(kp + t * 1024);
            short8 Kf1 = *(const short8*)(kp + t * 1024 + 512);
            short8 Vf0 = *(const short8*)(vpA + t * 32);
            short8 Vf1 = *(const short8*)(vpA + t * 32 + 1024);
            short8 Vf2 = *(const short8*)(vpB + t * 32);
            short8 Vf3 = *(const short8*)(vpB + t * 32 + 1024);

            // ---- S^T = K.Q^T (col=query, 4 consecutive keys/lane) ----
            f32x4 S00 = __builtin_amdgcn_mfma_f32_16x16x32_bf16(Kf0, Qf0, zero4, 0, 0, 0);
            f32x4 S01 = __builtin_amdgcn_mfma_f32_16x16x32_bf16(Kf1, Qf0, zero4, 0, 0, 0);
            f32x4 S10 = __builtin_amdgcn_mfma_f32_16x16x32_bf16(Kf0, Qf1, zero4, 0, 0, 0);
            f32x4 S11 = __builtin_amdgcn_mfma_f32_16x16x32_bf16(Kf1, Qf1, zero4, 0, 0, 0);

            // ---- exp2 + pack + swizzled wave-private P write ----
            int k0 = ((4 * t +     ch) ^ sw) * 8;
            int k1 = ((4 * t + 2 + ch) ^ sw) * 8;
            uint2 w;
            w.x = pack2bf(__builtin_amdgcn_exp2f(S00.x), __builtin_amdgcn_exp2f(S00.y));
            w.y = pack2bf(__builtin_amdgcn_exp2f(S00.z), __builtin_amdgcn_exp2f(S00.w));
            *(uint2*)&Pw[wr0 + k0] = w;
            w.x = pack2bf(__builtin_amdgcn_exp2f(S01.x), __builtin_amdgcn_exp2f(S01.y));
            w.y = pack2bf(__builtin_amdgcn_exp2f(S01.z), __builtin_amdgcn_exp2f(S01.w));
            *(uint2*)&Pw[wr0 + k1] = w;
            w.x = pack2bf(__builtin_amdgcn_exp2f(S10.x), __builtin_amdgcn_exp2f(S10.y));
            w.y = pack2bf(__builtin_amdgcn_exp2f(S10.z), __builtin_amdgcn_exp2f(S10.w));
            *(uint2*)&Pw[wr1 + k0] = w;
            w.x = pack2bf(__builtin_amdgcn_exp2f(S11.x), __builtin_amdgcn_exp2f(S11.y));
            w.y = pack2bf(__builtin_amdgcn_exp2f(S11.z), __builtin_amdgcn_exp2f(S11.w));
            *(uint2*)&Pw[wr1 + k1] = w;

            // ---- A-fragments back (same-wave lgkm dependency only) ----
            int rk = ((4 * t + rdc) ^ sw) * 8;
            short8 Ap0 = *(const short8*)&Pw[m16 * 64 + rk];
            short8 Ap1 = *(const short8*)&Pw[(16 + m16) * 64 + rk];

            // ---- PV + ones row-sum ----
            Do[0] = __builtin_amdgcn_mfma_f32_16x16x32_bf16(Ap0, ones, Do[0], 0, 0, 0);
            Do[1] = __builtin_amdgcn_mfma_f32_16x16x32_bf16(Ap1, ones, Do[1], 0, 0, 0);
            acc[0][0] = __builtin_amdgcn_mfma_f32_16x16x32_bf16(Ap0, Vf0, acc[0][0], 0, 0, 0);
            acc[0][1] = __builtin_amdgcn_mfma_f32_16x16x32_bf16(Ap0, Vf1, acc[0][1], 0, 0, 0);
            acc[0][2] = __builtin_amdgcn_mfma_f32_16x16x32_bf16(Ap0, Vf2, acc[0][2], 0, 0, 0);
            acc[0][3] = __builtin_amdgcn_mfma_f32_16x16x32_bf16(Ap0, Vf3, acc[0][3], 0, 0, 0);
            acc[1][0] = __builtin_amdgcn_mfma_f32_16x16x32_bf16(Ap1, Vf0, acc[1][0], 0, 0, 0);
            acc[1][1] = __builtin_amdgcn_mfma_f32_16x16x32_bf16(Ap1, Vf1, acc[1][1], 0, 0, 0);
            acc[1][2] = __builtin_amdgcn_mfma_f32_16x16x32_bf16(Ap1, Vf2, acc[1][2], 0, 0, 0);
            acc[1][3] = __builtin_amdgcn_mfma_f32_16x16x32_bf16(Ap1, Vf3, acc[1][3], 0, 0, 0);
        }
        kp  += 2048;     // 64 keys * 32 shorts
        vpA += 16384;    // one 256x64 tile
        vpB += 16384;
    }

    // ---- combine key-split halves through LDS ----
    __syncthreads();
    float* red = (float*)Smem;
    if (wv >= 2) {
        float* dst = red + (size_t)(wv - 2) * (64 * 44) + lane * 44;
        #pragma unroll
        for (int mt = 0; mt < 2; ++mt)
            #pragma unroll
            for (int cs = 0; cs < 4; ++cs)
                *(f32x4*)&dst[(mt * 4 + cs) * 4] = acc[mt][cs];
        *(f32x4*)&dst[32] = Do[0];
        *(f32x4*)&dst[36] = Do[1];
    }
    __syncthreads();
    if (wv < 2) {
        float* src = red + (size_t)wv * (64 * 44) + lane * 44;
        #pragma unroll
        for (int mt = 0; mt < 2; ++mt)
            #pragma unroll
            for (int cs = 0; cs < 4; ++cs) {
                f32x4 p = *(const f32x4*)&src[(mt * 4 + cs) * 4];
                acc[mt][cs].x += p.x; acc[mt][cs].y += p.y;
                acc[mt][cs].z += p.z; acc[mt][cs].w += p.w;
            }
        f32x4 d0 = *(const f32x4*)&src[32];
        f32x4 d1 = *(const f32x4*)&src[36];
        Do[0].x += d0.x; Do[0].y += d0.y; Do[0].z += d0.z; Do[0].w += d0.w;
        Do[1].x += d1.x; Do[1].y += d1.y; Do[1].z += d1.z; Do[1].w += d1.w;

        f32x4 inv[2];
        #pragma unroll
        for (int mt = 0; mt < 2; ++mt) {
            inv[mt].x = __builtin_amdgcn_rcpf(Do[mt].x);
            inv[mt].y = __builtin_amdgcn_rcpf(Do[mt].y);
            inv[mt].z = __builtin_amdgcn_rcpf(Do[mt].z);
            inv[mt].w = __builtin_amdgcn_rcpf(Do[mt].w);
        }

        float* ob = out + ((size_t)b * 256 + c0) * 4096 + q0;
        #pragma unroll
        for (int mt = 0; mt < 2; ++mt)
            #pragma unroll
            for (int cs = 0; cs < 4; ++cs) {
                float4 o;
                o.x = acc[mt][cs].x * inv[mt].x;
                o.y = acc[mt][cs].y * inv[mt].y;
                o.z = acc[mt][cs].z * inv[mt].z;
                o.w = acc[mt][cs].w * inv[mt].w;
                *(float4*)(ob + (size_t)(cs * 16 + m16) * 4096 + mt * 16 + qd * 4) = o;
            }
    }
}

// ---------------------------------------------------------------------------
// Workspace: wq 320x256 bf16 | scale/off 320 f32 | q_t,k_t [b][n][32] bf16 |
// v_ws tile-blocked [b*64+kt][256][64] bf16. Total ~10.7 MB.
// ---------------------------------------------------------------------------
extern "C" void kernel_launch(void* const* d_in, const int* in_sizes, int n_in,
                              void* d_out, int out_size, void* d_ws, size_t ws_size,
                              hipStream_t stream)
{
    const float* x1  = (const float*)d_in[0];
    const float* x2  = (const float*)d_in[1];
    const float* qw  = (const float*)d_in[2];
    const float* qb  = (const float*)d_in[3];
    const float* qg  = (const float*)d_in[4];
    const float* qbe = (const float*)d_in[5];
    const float* qm  = (const float*)d_in[6];
    const float* qv  = (const float*)d_in[7];
    const float* kw  = (const float*)d_in[8];
    const float* kb  = (const float*)d_in[9];
    const float* kg  = (const float*)d_in[10];
    const float* kbe = (const float*)d_in[11];
    const float* km  = (const float*)d_in[12];
    const float* kvv = (const float*)d_in[13];
    const float* vw  = (const float*)d_in[14];
    const float* vb  = (const float*)d_in[15];
    const float* vg  = (const float*)d_in[16];
    const float* vbe = (const float*)d_in[17];
    const float* vm  = (const float*)d_in[18];
    const float* vv  = (const float*)d_in[19];

    char* ws = (char*)d_ws;
    unsigned short* wq   = (unsigned short*)(ws + 0);
    float*          scale= (float*)(ws + 163840);
    float*          off  = (float*)(ws + 165120);
    unsigned short* q_t  = (unsigned short*)(ws + 166400);
    unsigned short* k_t  = (unsigned short*)(ws + 166400 + 1048576);
    unsigned short* v_ws = (unsigned short*)(ws + 166400 + 2097152);

    prep_kernel<<<320, 64, 0, stream>>>(qw, qb, qg, qbe, qm, qv,
                                        kw, kb, kg, kbe, km, kvv,
                                        vw, vb, vg, vbe, vm, vv,
                                        wq, scale, off);
    proj_kernel<<<1024, 256, 0, stream>>>(x1, x2, wq, scale, off, q_t, k_t, v_ws);
    flash_kernel<<<1024, 256, 0, stream>>>(q_t, k_t, v_ws, (float*)d_out);
}

// Round 5
// 223.640 us; speedup vs baseline: 1.3220x; 1.2391x over previous
//
#include <hip/hip_runtime.h>

using short8   = __attribute__((ext_vector_type(8))) short;
using f32x4    = __attribute__((ext_vector_type(4))) float;
using ushort4v = __attribute__((ext_vector_type(4))) unsigned short;

#define BN_EPS 1e-5f
// log2(e)/sqrt(32): folded into q projection so softmax uses native exp2
#define ATT_SCALE_LOG2E 0.2550348347988049f

__device__ __forceinline__ unsigned short f2bf(float f) {
    union { float f; unsigned u; } v; v.f = f;
    return (unsigned short)((v.u + 0x7FFFu + ((v.u >> 16) & 1u)) >> 16);  // RNE
}

// pack two f32 -> two bf16 (round-half-up): a in low 16, b in high 16
__device__ __forceinline__ unsigned pack2bf(float a, float b) {
    union { float f; unsigned u; } ua, ub; ua.f = a; ub.f = b;
    return __builtin_amdgcn_perm(ub.u + 0x8000u, ua.u + 0x8000u, 0x07060302u);
}

// async global->LDS, 16B per lane. gp: per-lane global src. lp: wave-uniform
// LDS base (HW adds lane*16).
__device__ __forceinline__ void glds16(const void* gp, void* lp) {
    __builtin_amdgcn_global_load_lds(
        (const __attribute__((address_space(1))) unsigned*)gp,
        (__attribute__((address_space(3))) unsigned*)lp, 16, 0, 0);
}

// ---------------------------------------------------------------------------
// Kernel 0: weights -> bf16; fold conv-bias + BN into per-row (scale, offset).
// Rows: 0-31 q, 32-63 k, 64-319 v.
// ---------------------------------------------------------------------------
__global__ void prep_kernel(
    const float* __restrict__ qw, const float* __restrict__ qb,
    const float* __restrict__ qg, const float* __restrict__ qbe,
    const float* __restrict__ qm, const float* __restrict__ qv,
    const float* __restrict__ kw, const float* __restrict__ kb,
    const float* __restrict__ kg, const float* __restrict__ kbe,
    const float* __restrict__ km, const float* __restrict__ kvv,
    const float* __restrict__ vw, const float* __restrict__ vb,
    const float* __restrict__ vg, const float* __restrict__ vbe,
    const float* __restrict__ vm, const float* __restrict__ vv,
    unsigned short* __restrict__ wq, float* __restrict__ scale,
    float* __restrict__ off)
{
    int r = blockIdx.x;      // 0..319
    int t = threadIdx.x;     // 0..63
    const float *wsrc, *g, *be, *mn, *vr, *bi;
    int rl;
    if (r < 32)      { rl = r;      wsrc = qw; g = qg; be = qbe; mn = qm; vr = qv;  bi = qb; }
    else if (r < 64) { rl = r - 32; wsrc = kw; g = kg; be = kbe; mn = km; vr = kvv; bi = kb; }
    else             { rl = r - 64; wsrc = vw; g = vg; be = vbe; mn = vm; vr = vv;  bi = vb; }

    float4 w4 = *(const float4*)(wsrc + rl * 256 + t * 4);
    ushort4v o;
    o.x = f2bf(w4.x); o.y = f2bf(w4.y); o.z = f2bf(w4.z); o.w = f2bf(w4.w);
    *(ushort4v*)(wq + r * 256 + t * 4) = o;

    if (t == 0) {
        float inv = g[rl] * rsqrtf(vr[rl] + BN_EPS);
        float ofv = bi[rl] * inv + be[rl] - mn[rl] * inv;
        float s = (r < 32) ? ATT_SCALE_LOG2E : 1.0f;
        scale[r] = inv * s;
        off[r]   = ofv * s;
    }
}

// ---------------------------------------------------------------------------
// Kernel 1: projections. bx = ((b*64+nt)<<2) | g ; g=0: q(x1), g=1: k(x2),
// g=2: v rows 0-127 (x2), g=3: v rows 128-255 (x2).
// q_t/k_t: [b][n][32] bf16.  v_ws: TILE-BLOCKED [b*64+nt][256][64] bf16.
// ---------------------------------------------------------------------------
#define XT_PITCH 264

__global__ __launch_bounds__(256, 4) void proj_kernel(
    const float* __restrict__ x1, const float* __restrict__ x2,
    const unsigned short* __restrict__ wq,
    const float* __restrict__ scale, const float* __restrict__ off,
    unsigned short* __restrict__ q_t, unsigned short* __restrict__ k_t,
    unsigned short* __restrict__ v_ws)
{
    __shared__ __align__(16) unsigned short Xt[64 * XT_PITCH];   // 33792 B
    int bx = blockIdx.x;
    int g  = bx & 3;
    int t2 = bx >> 2;
    int nt = t2 & 63;
    int b  = t2 >> 6;
    int n0 = nt * 64;
    int tid = threadIdx.x;
    int wv = tid >> 6, lane = tid & 63;
    int m16 = lane & 15, qd = lane >> 4;

    const float* xb = ((g == 0) ? x1 : x2) + (size_t)b * 256 * 4096 + n0 + lane;

    // octet-gather transpose: n = lane, channels 8*o..8*o+7, o = wv*8+i
    #pragma unroll 2
    for (int i = 0; i < 8; ++i) {
        int o = wv * 8 + i;                       // 0..31
        const float* src = xb + (size_t)(o * 8) * 4096;
        uint4 dw;
        dw.x = pack2bf(src[0],                src[(size_t)1 * 4096]);
        dw.y = pack2bf(src[(size_t)2 * 4096], src[(size_t)3 * 4096]);
        dw.z = pack2bf(src[(size_t)4 * 4096], src[(size_t)5 * 4096]);
        dw.w = pack2bf(src[(size_t)6 * 4096], src[(size_t)7 * 4096]);
        *(uint4*)&Xt[lane * XT_PITCH + o * 8] = dw;
    }
    __syncthreads();

    f32x4 zero4 = {0.f, 0.f, 0.f, 0.f};

    if (g < 2) {
        int rb = g * 32;
        f32x4 acc0 = zero4, acc1 = zero4;
        #pragma unroll 2
        for (int s = 0; s < 8; ++s) {
            short8 w0 = *(const short8*)(wq + (size_t)(rb +      m16) * 256 + s * 32 + qd * 8);
            short8 w1 = *(const short8*)(wq + (size_t)(rb + 16 + m16) * 256 + s * 32 + qd * 8);
            short8 xf = *(const short8*)&Xt[(16 * wv + m16) * XT_PITCH + s * 32 + qd * 8];
            acc0 = __builtin_amdgcn_mfma_f32_16x16x32_bf16(w0, xf, acc0, 0, 0, 0);
            acc1 = __builtin_amdgcn_mfma_f32_16x16x32_bf16(w1, xf, acc1, 0, 0, 0);
        }
        unsigned short* dst = (g == 0) ? q_t : k_t;
        int ncol = n0 + 16 * wv + m16;
        #pragma unroll
        for (int tm = 0; tm < 2; ++tm) {
            f32x4 acc = tm ? acc1 : acc0;
            int r0 = 16 * tm + 4 * qd;
            float4 sc = *(const float4*)(scale + rb + r0);
            float4 of = *(const float4*)(off   + rb + r0);
            ushort4v o;
            o.x = f2bf(acc.x * sc.x + of.x);
            o.y = f2bf(acc.y * sc.y + of.y);
            o.z = f2bf(acc.z * sc.z + of.z);
            o.w = f2bf(acc.w * sc.w + of.w);
            *(ushort4v*)(dst + ((size_t)b * 4096 + ncol) * 32 + r0) = o;
        }
    } else {
        int cb = (g - 2) * 128;
        f32x4 acc[2][4];
        #pragma unroll
        for (int rr = 0; rr < 2; ++rr)
            #pragma unroll
            for (int tm = 0; tm < 4; ++tm) acc[rr][tm] = zero4;
        #pragma unroll 2
        for (int s = 0; s < 8; ++s) {
            short8 xf[4];
            #pragma unroll
            for (int tm = 0; tm < 4; ++tm)
                xf[tm] = *(const short8*)&Xt[(16 * tm + m16) * XT_PITCH + s * 32 + qd * 8];
            #pragma unroll
            for (int rr = 0; rr < 2; ++rr) {
                short8 wf = *(const short8*)(wq + (size_t)(64 + cb + rr * 64 + 16 * wv + m16) * 256 + s * 32 + qd * 8);
                #pragma unroll
                for (int tm = 0; tm < 4; ++tm)
                    acc[rr][tm] = __builtin_amdgcn_mfma_f32_16x16x32_bf16(xf[tm], wf, acc[rr][tm], 0, 0, 0);
            }
        }
        unsigned short* vt = v_ws + (size_t)(b * 64 + nt) * 256 * 64;
        #pragma unroll
        for (int rr = 0; rr < 2; ++rr) {
            int c = cb + rr * 64 + 16 * wv + m16;
            float sc = scale[64 + c], of = off[64 + c];
            #pragma unroll
            for (int tm = 0; tm < 4; ++tm) {
                int nloc = 16 * tm + 4 * qd;
                ushort4v o;
                o.x = f2bf(acc[rr][tm].x * sc + of);
                o.y = f2bf(acc[rr][tm].y * sc + of);
                o.z = f2bf(acc[rr][tm].z * sc + of);
                o.w = f2bf(acc[rr][tm].w * sc + of);
                *(ushort4v*)(vt + c * 64 + nloc) = o;
            }
        }
    }
}

// ---------------------------------------------------------------------------
// Kernel 2: flash attention with ASYNC LDS STAGING (m97 pattern).
// Block = 2 waves, 64 queries (32/wave), 64 channels (cg), ALL 4096 keys.
// Grid 1024 = 4 blocks/CU. Per 64-key tile the block DMAs K (4KB) + V-slice
// (8KB) into a double-buffered LDS region via global_load_lds width=16,
// issued right after the tile barrier -> a full tile of compute hides the
// latency. 16B-granule XOR swizzle is applied on the GLOBAL source addresses
// so the LDS image is swizzled while the DMA stays lane*16-contiguous; all
// b128 fragment reads are then bank-uniform (8 dwords/bank = floor).
// P: wave-private XOR-swizzled LDS round-trip (r4 scheme). Row sums via VALU.
// No cross-wave combine: pure shfl epilogue.
// ---------------------------------------------------------------------------
__global__ __launch_bounds__(128, 2) void flash_kernel(
    const unsigned short* __restrict__ q_t, const unsigned short* __restrict__ k_t,
    const unsigned short* __restrict__ v_ws, float* __restrict__ out)
{
    __shared__ __align__(16) unsigned char Smem[32768]; // kv dbuf 2x12KB + P 2x4KB

    int bx  = blockIdx.x;
    int cg  = bx & 3;
    int b   = (bx >> 2) & 3;
    int qg  = bx >> 4;             // 0..63
    int tid = threadIdx.x;
    int wv  = tid >> 6, lane = tid & 63;
    int m16 = lane & 15, qd = lane >> 4;

    int q0 = qg * 64 + wv * 32;
    int c0 = cg * 64;
    int sw = m16 & 7;

    // ---- staging address prep (XOR swizzle folded into global offsets) ----
    int kg[2], vg[4];
    int kl[2], vl[4];
    #pragma unroll
    for (int u = 0; u < 2; ++u) {
        int slot = (wv * 2 + u) * 64 + lane;          // K: 4B-granule rows of 4
        int row = slot >> 2, pos = slot & 3;
        kg[u] = (row * 4 + (pos ^ (row & 3))) * 16;
        kl[u] = (wv * 2 + u) * 1024;
    }
    #pragma unroll
    for (int u = 0; u < 4; ++u) {
        int slot = (wv * 4 + u) * 64 + lane;          // V: granule rows of 8
        int row = slot >> 3, pos = slot & 7;
        vg[u] = (row * 8 + (pos ^ (row & 7))) * 16;
        vl[u] = (wv * 4 + u) * 1024;
    }

    const char* kbase = (const char*)k_t + (size_t)b * 262144;
    const char* vbase = (const char*)v_ws + (size_t)b * 2097152 + (size_t)c0 * 128;
    char* smem = (char*)Smem;

    // ---- persistent Q fragments ----
    const unsigned short* qb = q_t + (size_t)b * 4096 * 32;
    short8 Qf0 = *(const short8*)(qb + (size_t)(q0 +      m16) * 32 + qd * 8);
    short8 Qf1 = *(const short8*)(qb + (size_t)(q0 + 16 + m16) * 32 + qd * 8);

    f32x4 zero4 = {0.f, 0.f, 0.f, 0.f};
    f32x4 acc[2][4];
    #pragma unroll
    for (int mt = 0; mt < 2; ++mt)
        #pragma unroll
        for (int cs = 0; cs < 4; ++cs) acc[mt][cs] = zero4;
    float lsum0 = 0.f, lsum1 = 0.f;

    unsigned short* Pw = (unsigned short*)(smem + 24576 + wv * 4096);
    int wr0 = m16 * 64 + (qd & 1) * 4;
    int wr1 = wr0 + 16 * 64;
    int ch  = qd >> 1;
    int kro = m16 * 64 + ((qd ^ (m16 & 3)) << 4);     // K frag byte offset

    // prologue: stage tile 0 into buf 0
    {
        const char* ks = kbase; const char* vs = vbase;
        glds16(ks + kg[0], smem + kl[0]); glds16(ks + kg[1], smem + kl[1]);
        glds16(vs + vg[0], smem + 4096 + vl[0]); glds16(vs + vg[1], smem + 4096 + vl[1]);
        glds16(vs + vg[2], smem + 4096 + vl[2]); glds16(vs + vg[3], smem + 4096 + vl[3]);
    }

    #pragma unroll 1
    for (int it = 0; it < 64; ++it) {
        int z = it & 1;
        __syncthreads();   // buf z complete (its DMA was issued a full tile ago)

        if (it < 63) {     // stage next tile into buf z^1
            const char* ks = kbase + (size_t)(it + 1) * 4096;
            const char* vs = vbase + (size_t)(it + 1) * 32768;
            char* kd = smem + (z ^ 1) * 12288;
            char* vd = kd + 4096;
            glds16(ks + kg[0], kd + kl[0]); glds16(ks + kg[1], kd + kl[1]);
            glds16(vs + vg[0], vd + vl[0]); glds16(vs + vg[1], vd + vl[1]);
            glds16(vs + vg[2], vd + vl[2]); glds16(vs + vg[3], vd + vl[3]);
        }

        const char* Kb = smem + z * 12288;
        const char* Vb = Kb + 4096;

        #pragma unroll
        for (int t = 0; t < 2; ++t) {
            // ---- fragments from LDS (swizzled, bank-uniform) ----
            short8 Kf0 = *(const short8*)(Kb + t * 2048 + kro);
            short8 Kf1 = *(const short8*)(Kb + t * 2048 + 1024 + kro);
            int vro = ((t * 4 + qd) ^ sw) << 4;
            short8 Vf0 = *(const short8*)(Vb + (      m16) * 128 + vro);
            short8 Vf1 = *(const short8*)(Vb + (16 + m16) * 128 + vro);
            short8 Vf2 = *(const short8*)(Vb + (32 + m16) * 128 + vro);
            short8 Vf3 = *(const short8*)(Vb + (48 + m16) * 128 + vro);

            // ---- S^T = K.Q^T ----
            f32x4 S00 = __builtin_amdgcn_mfma_f32_16x16x32_bf16(Kf0, Qf0, zero4, 0, 0, 0);
            f32x4 S01 = __builtin_amdgcn_mfma_f32_16x16x32_bf16(Kf1, Qf0, zero4, 0, 0, 0);
            f32x4 S10 = __builtin_amdgcn_mfma_f32_16x16x32_bf16(Kf0, Qf1, zero4, 0, 0, 0);
            f32x4 S11 = __builtin_amdgcn_mfma_f32_16x16x32_bf16(Kf1, Qf1, zero4, 0, 0, 0);

            // ---- exp2 + row-sum + pack + swizzled wave-private P write ----
            int k0 = ((4 * t +     ch) ^ sw) * 8;
            int k1 = ((4 * t + 2 + ch) ^ sw) * 8;
            {
                float a0 = __builtin_amdgcn_exp2f(S00.x), a1 = __builtin_amdgcn_exp2f(S00.y);
                float a2 = __builtin_amdgcn_exp2f(S00.z), a3 = __builtin_amdgcn_exp2f(S00.w);
                float a4 = __builtin_amdgcn_exp2f(S01.x), a5 = __builtin_amdgcn_exp2f(S01.y);
                float a6 = __builtin_amdgcn_exp2f(S01.z), a7 = __builtin_amdgcn_exp2f(S01.w);
                lsum0 += ((a0 + a1) + (a2 + a3)) + ((a4 + a5) + (a6 + a7));
                uint2 w0; w0.x = pack2bf(a0, a1); w0.y = pack2bf(a2, a3);
                *(uint2*)&Pw[wr0 + k0] = w0;
                uint2 w1; w1.x = pack2bf(a4, a5); w1.y = pack2bf(a6, a7);
                *(uint2*)&Pw[wr0 + k1] = w1;
            }
            {
                float a0 = __builtin_amdgcn_exp2f(S10.x), a1 = __builtin_amdgcn_exp2f(S10.y);
                float a2 = __builtin_amdgcn_exp2f(S10.z), a3 = __builtin_amdgcn_exp2f(S10.w);
                float a4 = __builtin_amdgcn_exp2f(S11.x), a5 = __builtin_amdgcn_exp2f(S11.y);
                float a6 = __builtin_amdgcn_exp2f(S11.z), a7 = __builtin_amdgcn_exp2f(S11.w);
                lsum1 += ((a0 + a1) + (a2 + a3)) + ((a4 + a5) + (a6 + a7));
                uint2 w0; w0.x = pack2bf(a0, a1); w0.y = pack2bf(a2, a3);
                *(uint2*)&Pw[wr1 + k0] = w0;
                uint2 w1; w1.x = pack2bf(a4, a5); w1.y = pack2bf(a6, a7);
                *(uint2*)&Pw[wr1 + k1] = w1;
            }

            // ---- A-fragments back (same-wave lgkm dependency only) ----
            int rk = ((4 * t + qd) ^ sw) * 8;
            short8 Ap0 = *(const short8*)&Pw[m16 * 64 + rk];
            short8 Ap1 = *(const short8*)&Pw[(16 + m16) * 64 + rk];

            // ---- PV ----
            acc[0][0] = __builtin_amdgcn_mfma_f32_16x16x32_bf16(Ap0, Vf0, acc[0][0], 0, 0, 0);
            acc[0][1] = __builtin_amdgcn_mfma_f32_16x16x32_bf16(Ap0, Vf1, acc[0][1], 0, 0, 0);
            acc[0][2] = __builtin_amdgcn_mfma_f32_16x16x32_bf16(Ap0, Vf2, acc[0][2], 0, 0, 0);
            acc[0][3] = __builtin_amdgcn_mfma_f32_16x16x32_bf16(Ap0, Vf3, acc[0][3], 0, 0, 0);
            acc[1][0] = __builtin_amdgcn_mfma_f32_16x16x32_bf16(Ap1, Vf0, acc[1][0], 0, 0, 0);
            acc[1][1] = __builtin_amdgcn_mfma_f32_16x16x32_bf16(Ap1, Vf1, acc[1][1], 0, 0, 0);
            acc[1][2] = __builtin_amdgcn_mfma_f32_16x16x32_bf16(Ap1, Vf2, acc[1][2], 0, 0, 0);
            acc[1][3] = __builtin_amdgcn_mfma_f32_16x16x32_bf16(Ap1, Vf3, acc[1][3], 0, 0, 0);
        }
    }

    // ---- softmax denominators (per query = S^T col = m16) ----
    lsum0 += __shfl_xor(lsum0, 16); lsum0 += __shfl_xor(lsum0, 32);
    lsum1 += __shfl_xor(lsum1, 16); lsum1 += __shfl_xor(lsum1, 32);
    float li0 = __builtin_amdgcn_rcpf(lsum0);
    float li1 = __builtin_amdgcn_rcpf(lsum1);
    float lr0[4], lr1[4];
    #pragma unroll
    for (int r = 0; r < 4; ++r) {
        lr0[r] = __shfl(li0, 4 * qd + r);
        lr1[r] = __shfl(li1, 4 * qd + r);
    }

    float* ob = out + ((size_t)b * 256 + c0) * 4096 + q0;
    #pragma unroll
    for (int cs = 0; cs < 4; ++cs) {
        float4 o;
        o.x = acc[0][cs].x * lr0[0];
        o.y = acc[0][cs].y * lr0[1];
        o.z = acc[0][cs].z * lr0[2];
        o.w = acc[0][cs].w * lr0[3];
        *(float4*)(ob + (size_t)(cs * 16 + m16) * 4096 + qd * 4) = o;
        o.x = acc[1][cs].x * lr1[0];
        o.y = acc[1][cs].y * lr1[1];
        o.z = acc[1][cs].z * lr1[2];
        o.w = acc[1][cs].w * lr1[3];
        *(float4*)(ob + (size_t)(cs * 16 + m16) * 4096 + 16 + qd * 4) = o;
    }
}

// ---------------------------------------------------------------------------
// Workspace: wq 320x256 bf16 | scale/off 320 f32 | q_t,k_t [b][n][32] bf16 |
// v_ws tile-blocked [b*64+kt][256][64] bf16. Total ~10.7 MB.
// ---------------------------------------------------------------------------
extern "C" void kernel_launch(void* const* d_in, const int* in_sizes, int n_in,
                              void* d_out, int out_size, void* d_ws, size_t ws_size,
                              hipStream_t stream)
{
    const float* x1  = (const float*)d_in[0];
    const float* x2  = (const float*)d_in[1];
    const float* qw  = (const float*)d_in[2];
    const float* qb  = (const float*)d_in[3];
    const float* qg  = (const float*)d_in[4];
    const float* qbe = (const float*)d_in[5];
    const float* qm  = (const float*)d_in[6];
    const float* qv  = (const float*)d_in[7];
    const float* kw  = (const float*)d_in[8];
    const float* kb  = (const float*)d_in[9];
    const float* kg  = (const float*)d_in[10];
    const float* kbe = (const float*)d_in[11];
    const float* km  = (const float*)d_in[12];
    const float* kvv = (const float*)d_in[13];
    const float* vw  = (const float*)d_in[14];
    const float* vb  = (const float*)d_in[15];
    const float* vg  = (const float*)d_in[16];
    const float* vbe = (const float*)d_in[17];
    const float* vm  = (const float*)d_in[18];
    const float* vv  = (const float*)d_in[19];

    char* ws = (char*)d_ws;
    unsigned short* wq   = (unsigned short*)(ws + 0);
    float*          scale= (float*)(ws + 163840);
    float*          off  = (float*)(ws + 165120);
    unsigned short* q_t  = (unsigned short*)(ws + 166400);
    unsigned short* k_t  = (unsigned short*)(ws + 166400 + 1048576);
    unsigned short* v_ws = (unsigned short*)(ws + 166400 + 2097152);

    prep_kernel<<<320, 64, 0, stream>>>(qw, qb, qg, qbe, qm, qv,
                                        kw, kb, kg, kbe, km, kvv,
                                        vw, vb, vg, vbe, vm, vv,
                                        wq, scale, off);
    proj_kernel<<<1024, 256, 0, stream>>>(x1, x2, wq, scale, off, q_t, k_t, v_ws);
    flash_kernel<<<1024, 128, 0, stream>>>(q_t, k_t, v_ws, (float*)d_out);
}